// Round 7
// baseline (167.183 us; speedup 1.0000x reference)
//
#include <hip/hip_runtime.h>
#include <hip/hip_bf16.h>
#include <math.h>

// All scratch in module-owned device memory: d_ws is never touched.
// Layout (floats):
#define OFF_BEFF  0        // 512
#define OFF_LB    512      // 384
#define OFF_U     1024     // 4096 (buf[k][d] = W_eff[k][d] = Q[d][k])
#define OFF_FEATS 5120     // 256*48 = 12288
#define OFF_DENP  17408    // 256
#define OFF_NUMP  17664    // 256
#define OFF_SQP   17920    // 256*48 = 12288
#define WS_TOTAL  30208

__device__ float g_ws[WS_TOTAL];

static __device__ __forceinline__ float wred64(float v){
  #pragma unroll
  for (int m = 32; m >= 1; m >>= 1) v += __shfl_xor(v, m, 64);
  return v;
}

// ---------------- K1: QR (LAPACK Householder), sigmoid(beta), Legendre basis --------
__global__ __launch_bounds__(256) void k1_prep(const float* __restrict__ Wp,
                                               const float* __restrict__ beta){
  int tid = threadIdx.x;
  __shared__ float p1s[128], p2s[128], nrm[2];
  for (int d = tid; d < 512; d += 256){
    float b = beta[d];
    g_ws[OFF_BEFF + d] = 1.0f/(1.0f + expf(-b));
  }
  if (tid < 128){
    float t = -1.0f + 2.0f*(float)tid/127.0f;
    p1s[tid] = t;
    p2s[tid] = 0.5f*(3.0f*t*t - 1.0f);
  }
  __syncthreads();
  if (tid == 0){
    float a = 0, b = 0;
    for (int i = 0; i < 128; i++){ a += p1s[i]*p1s[i]; b += p2s[i]*p2s[i]; }
    nrm[0] = sqrtf(fmaxf(a, 1e-6f));
    nrm[1] = sqrtf(fmaxf(b, 1e-6f));
  }
  __syncthreads();
  if (tid < 128){
    g_ws[OFF_LB + 0*128 + tid] = 1.0f/sqrtf(128.0f);
    g_ws[OFF_LB + 1*128 + tid] = p1s[tid]/nrm[0];
    g_ws[OFF_LB + 2*128 + tid] = p2s[tid]/nrm[1];
  }
  // ---- QR of A = W_proj^T (512 x 8), wave 0, LAPACK sgeqrf+sorgqr convention ----
  if (tid < 64){
    int l = tid;
    float A[8][8], Q[8][8], tau[8];
    #pragma unroll
    for (int c = 0; c < 8; c++)
      #pragma unroll
      for (int p = 0; p < 8; p++)
        A[c][p] = Wp[c*512 + p*64 + l];   // row = p*64+l
    #pragma unroll
    for (int j = 0; j < 8; j++){
      float alpha = __shfl(A[j][0], j, 64);
      float ssq = 0.0f;
      #pragma unroll
      for (int p = 0; p < 8; p++){
        bool live = (p > 0) || (l > j);
        float v = A[j][p];
        ssq += live ? v*v : 0.0f;
      }
      ssq = wred64(ssq);
      float tj, scale;
      if (ssq == 0.0f){ tj = 0.0f; scale = 0.0f; }
      else {
        float bta = -copysignf(sqrtf(alpha*alpha + ssq), alpha);
        tj = (bta - alpha)/bta;
        scale = 1.0f/(alpha - bta);
      }
      tau[j] = tj;
      #pragma unroll
      for (int p = 0; p < 8; p++){
        int row = p*64 + l;
        float v = A[j][p]*scale;
        A[j][p] = (row < j) ? 0.0f : (row == j ? 1.0f : v);
      }
      #pragma unroll
      for (int c = j+1; c < 8; c++){
        float d = 0.0f;
        #pragma unroll
        for (int p = 0; p < 8; p++) d += A[c][p]*A[j][p];
        d = wred64(d)*tj;
        #pragma unroll
        for (int p = 0; p < 8; p++) A[c][p] -= d*A[j][p];
      }
    }
    #pragma unroll
    for (int c = 0; c < 8; c++)
      #pragma unroll
      for (int p = 0; p < 8; p++)
        Q[c][p] = (p == 0 && l == c) ? 1.0f : 0.0f;
    #pragma unroll
    for (int j = 7; j >= 0; j--){
      #pragma unroll
      for (int c = 0; c < 8; c++){
        float d = 0.0f;
        #pragma unroll
        for (int p = 0; p < 8; p++) d += Q[c][p]*A[j][p];
        d = wred64(d)*tau[j];
        #pragma unroll
        for (int p = 0; p < 8; p++) Q[c][p] -= d*A[j][p];
      }
    }
    #pragma unroll
    for (int c = 0; c < 8; c++)
      #pragma unroll
      for (int p = 0; p < 8; p++)
        g_ws[OFF_U + c*512 + p*64 + l] = Q[c][p];   // buf[c][d] = Q[d][c]
  }
}

// ---------------- K23: per-bn projection + den + sort + feats -----------------------
__global__ __launch_bounds__(256) void k23_projsort(const float* __restrict__ x,
                                                    const float* __restrict__ vmask){
  int bn = blockIdx.x;                   // 0..255
  int b = bn >> 7, n = bn & 127;
  int tid = threadIdx.x;
  int lane32 = tid & 31, kg = tid >> 5;  // 8 k-groups x 32 lanes
  int l = tid & 63, wv = tid >> 6;
  __shared__ float xr[8][512];
  __shared__ float v[8][128];
  __shared__ float Bl[384];
  __shared__ float srt[4][128];
  __shared__ float pS[4][128];
  __shared__ int   pC[4][128];
  __shared__ float vmt[128];
  float u[16];
  #pragma unroll
  for (int j = 0; j < 16; j++) u[j] = g_ws[OFF_U + kg*512 + j*32 + lane32];
  for (int i = tid; i < 384; i += 256) Bl[i] = g_ws[OFF_LB + i];
  if (tid < 128) vmt[tid] = vmask[(b*128 + tid)*128 + n];
  float denacc = 0.0f;
  for (int tc = 0; tc < 16; tc++){
    __syncthreads();
    for (int i = tid; i < 1024; i += 256){
      int rr = i >> 7, j4 = i & 127;
      size_t base = ((((size_t)b*128 + (tc*8 + rr))*128) + n) << 9;
      *(float4*)&xr[rr][j4*4] = *(const float4*)(x + base + j4*4);
    }
    __syncthreads();
    for (int rr = 0; rr < 8; rr++){
      int t = tc*8 + rr;
      float p = 0.0f, sq = 0.0f;
      #pragma unroll
      for (int j = 0; j < 16; j++){
        float xv = xr[rr][j*32 + lane32];
        p += xv*u[j];
        sq += xv*xv;
      }
      #pragma unroll
      for (int m = 16; m >= 1; m >>= 1){
        p  += __shfl_xor(p, m, 64);
        sq += __shfl_xor(sq, m, 64);
      }
      if (lane32 == 0) v[kg][t] = p*vmt[t];
      if (tid == 0) denacc += sqrtf(sq);
    }
  }
  __syncthreads();
  if (tid == 0) g_ws[OFF_DENP + bn] = denacc;
  const float rinv = 22.627416997969522f;  // 1/reg, reg = 0.5*128^-0.5
  for (int kk = 0; kk < 2; kk++){
    int k = wv*2 + kk;
    float a  = v[k][2*l];
    float bb = v[k][2*l+1];
    float c0 = a*Bl[2*l]     + bb*Bl[2*l+1];
    float c1 = a*Bl[128+2*l] + bb*Bl[128+2*l+1];
    float c2 = a*Bl[256+2*l] + bb*Bl[256+2*l+1];
    c0 = wred64(c0); c1 = wred64(c1); c2 = wred64(c2);
    srt[wv][2*l] = 0.0f; srt[wv][2*l+1] = 0.0f;
    __syncthreads();
    int r0 = 0, r1 = 0;
    for (int j = 0; j < 128; j++){
      float vj = v[k][j];
      r0 += (vj < a)  || (vj == a  && j < 2*l);
      r1 += (vj < bb) || (vj == bb && j < 2*l+1);
    }
    srt[wv][r0] = a;
    srt[wv][r1] = bb;
    __syncthreads();
    bool viol0 = (srt[wv][2*l+1] - srt[wv][2*l] > rinv);
    bool viol1 = (2*l + 2 < 128) ? (srt[wv][2*l+2] - srt[wv][2*l+1] > rinv) : false;
    if (__any(viol0 || viol1)){
      if (l == 0){
        int top = -1;
        for (int i = 0; i < 128; i++){
          float y = (float)(128 - i)*rinv + srt[wv][i];
          top++; pS[wv][top] = y; pC[wv][top] = 1;
          while (top > 0 &&
                 pS[wv][top]*(float)pC[wv][top-1] > pS[wv][top-1]*(float)pC[wv][top]){
            pS[wv][top-1] += pS[wv][top];
            pC[wv][top-1] += pC[wv][top];
            top--;
          }
        }
        int i = 0;
        for (int blk = 0; blk <= top; blk++){
          float m = pS[wv][blk]/(float)pC[wv][blk];
          for (int c = 0; c < pC[wv][blk]; c++){
            srt[wv][i] = m - (float)(128 - i)*rinv;
            i++;
          }
        }
      }
    }
    if (l == 0){
      float* fb = g_ws + OFF_FEATS + bn*48 + k*6;
      float w0 = 0.1f*127.0f - 12.0f;
      float w1 = 0.5f*127.0f - 63.0f;
      float w2 = 0.9f*127.0f - 114.0f;
      fb[0] = (1.0f - w0)*srt[wv][12]  + w0*srt[wv][13];
      fb[1] = (1.0f - w1)*srt[wv][63]  + w1*srt[wv][64];
      fb[2] = (1.0f - w2)*srt[wv][114] + w2*srt[wv][115];
      fb[3] = c0; fb[4] = c1; fb[5] = c2;
    }
    __syncthreads();
  }
}

// ---------------- K45: per-bn head -> y, energy partials, h epilogue (f32 out) ------
__global__ __launch_bounds__(256) void k45_head_out(const float* __restrict__ x,
                                                    const float* __restrict__ vmask,
                                                    const float* __restrict__ W1,
                                                    const float* __restrict__ b1,
                                                    const float* __restrict__ W2,
                                                    float* __restrict__ outt){
  int bn = blockIdx.x;
  int b = bn >> 7, n = bn & 127;
  int tid = threadIdx.x;
  int l = tid & 63, wv = tid >> 6;
  __shared__ float fl[48];
  __shared__ float hl[768];
  __shared__ float sqlds[4][48];
  __shared__ float nred[4];
  if (tid < 48) fl[tid] = g_ws[OFF_FEATS + bn*48 + tid];
  __syncthreads();
  for (int off = tid; off < 768; off += 256){
    int f = off >> 4;
    float aa = fl[f]*W1[off] + b1[off];
    hl[off] = 0.5f*aa*(1.0f + erff(aa*0.70710678118654752f));  // exact GELU
  }
  __syncthreads();
  int d0 = 2*tid, d1 = 2*tid + 1;
  float be0 = g_ws[OFF_BEFF + d0], be1 = g_ws[OFF_BEFF + d1];
  float b20 = be0*be0, b21 = be1*be1;
  float y0 = 0.0f, y1 = 0.0f;
  for (int f = 0; f < 48; f++){
    float p0 = 0.0f, p1 = 0.0f;
    #pragma unroll
    for (int w = 0; w < 16; w++){
      float hw = hl[f*16 + w];
      float2 w2 = *(const float2*)(W2 + (((size_t)(f*16 + w)) << 9) + d0);
      p0 += hw*w2.x; p1 += hw*w2.y;
    }
    y0 += p0; y1 += p1;
    float sf = p0*p0*b20 + p1*p1*b21;
    sf = wred64(sf);
    if (l == 0) sqlds[wv][f] = sf;
  }
  float ns = y0*y0*b20 + y1*y1*b21;
  ns = wred64(ns);
  if (l == 0) nred[wv] = ns;
  __syncthreads();
  if (tid < 48) g_ws[OFF_SQP + bn*48 + tid] =
    sqlds[0][tid] + sqlds[1][tid] + sqlds[2][tid] + sqlds[3][tid];
  if (tid == 0) g_ws[OFF_NUMP + bn] = sqrtf(nred[0] + nred[1] + nred[2] + nred[3]);
  float by0 = be0*y0, by1 = be1*y1;
  for (int t = 0; t < 128; t++){
    size_t base = ((((size_t)b*128 + t)*128) + n) << 9;
    float vm = vmask[(b*128 + t)*128 + n];
    float2 xv = *(const float2*)(x + base + d0);
    float2 o;
    o.x = xv.x + vm*by0;
    o.y = xv.y + vm*by1;
    *(float2*)(outt + base + d0) = o;
  }
}

// ---------------- K6: finalize r and r_feat (f32 out) -------------------------------
__global__ __launch_bounds__(256) void k6_fin(float* __restrict__ outt){
  __shared__ float red[256];
  __shared__ float en[96];
  __shared__ float scal[2];
  int tid = threadIdx.x;
  red[tid] = g_ws[OFF_DENP + tid];
  __syncthreads();
  for (int s = 128; s > 0; s >>= 1){
    if (tid < s) red[tid] += red[tid + s];
    __syncthreads();
  }
  if (tid == 0) scal[0] = fmaxf(red[0]/32768.0f, 1e-9f);
  __syncthreads();
  red[tid] = g_ws[OFF_NUMP + tid];
  __syncthreads();
  for (int s = 128; s > 0; s >>= 1){
    if (tid < s) red[tid] += red[tid + s];
    __syncthreads();
  }
  if (tid == 0) scal[1] = red[0]/256.0f;
  __syncthreads();
  float den = scal[0];
  if (tid < 96){
    int b = tid/48, f = tid%48;
    float s = 0.0f;
    for (int j = 0; j < 128; j++) s += g_ws[OFF_SQP + (b*128 + j)*48 + f];
    en[tid] = sqrtf(128.0f*s);
  }
  __syncthreads();
  if (tid == 0) outt[16777216] = scal[1]/den;
  if (tid < 48) outt[16777217 + tid] = 0.5f*(en[tid] + en[48 + tid])/den;
}

extern "C" void kernel_launch(void* const* d_in, const int* in_sizes, int n_in,
                              void* d_out, int out_size, void* d_ws, size_t ws_size,
                              hipStream_t stream){
  (void)out_size; (void)d_ws; (void)ws_size;  // d_ws intentionally unused
  // Size-based dispatch: immune to any input-ordering assumption.
  const float *x=nullptr,*vm=nullptr,*Wp=nullptr,*W1=nullptr,*b1=nullptr,*W2=nullptr,*beta=nullptr;
  for (int i = 0; i < n_in; i++){
    int s = in_sizes[i];
    const float* p = (const float*)d_in[i];
    if      (s == 16777216) x = p;
    else if (s == 32768)    vm = p;
    else if (s == 4096)     Wp = p;
    else if (s == 393216)   W2 = p;
    else if (s == 512)      beta = p;
    else if (s == 768)      { if (!W1) W1 = p; else b1 = p; }
  }
  float* out = (float*)d_out;

  k1_prep<<<1, 256, 0, stream>>>(Wp, beta);
  k23_projsort<<<256, 256, 0, stream>>>(x, vm);
  k45_head_out<<<256, 256, 0, stream>>>(x, vm, W1, b1, W2, out);
  k6_fin<<<1, 256, 0, stream>>>(out);
}

// Round 8
// 116.784 us; speedup vs baseline: 1.4316x; 1.4316x over previous
//
#include <hip/hip_runtime.h>
#include <hip/hip_bf16.h>
#include <math.h>

// All scratch in module-owned device memory (d_ws unused).
// Layout (floats):
#define OFF_BEFF  0        // 512
#define OFF_B2    512      // 512
#define OFF_LB    1024     // 384
#define OFF_U     1408     // 4096 (buf[k][d] = W_eff[k][d] = Q[d][k])
#define OFF_FEATS 5504     // 256*48 = 12288
#define OFF_DENP  17792    // 1024
#define OFF_NUMP  18816    // 64
#define OFF_SQP   18880    // 128*48 = 6144
#define OFF_V     25024    // 256*8*128 = 262144  [bn][k][t]
#define OFF_Y     287168   // 256*512 = 131072   [bn][d]
#define WS_TOTAL  418240   // 1.67 MB

__device__ __align__(16) float g_ws[WS_TOTAL];

static __device__ __forceinline__ float wred64(float v){
  #pragma unroll
  for (int m = 32; m >= 1; m >>= 1) v += __shfl_xor(v, m, 64);
  return v;
}

// ---------------- K1: QR (LAPACK Householder), sigmoid(beta), Legendre basis --------
__global__ __launch_bounds__(256) void k1_prep(const float* __restrict__ Wp,
                                               const float* __restrict__ beta){
  int tid = threadIdx.x;
  __shared__ float p1s[128], p2s[128], nrm[2];
  for (int d = tid; d < 512; d += 256){
    float b = beta[d];
    float s = 1.0f/(1.0f + expf(-b));
    g_ws[OFF_BEFF + d] = s;
    g_ws[OFF_B2 + d] = s*s;
  }
  if (tid < 128){
    float t = -1.0f + 2.0f*(float)tid/127.0f;
    p1s[tid] = t;
    p2s[tid] = 0.5f*(3.0f*t*t - 1.0f);
  }
  __syncthreads();
  if (tid == 0){
    float a = 0, b = 0;
    for (int i = 0; i < 128; i++){ a += p1s[i]*p1s[i]; b += p2s[i]*p2s[i]; }
    nrm[0] = sqrtf(fmaxf(a, 1e-6f));
    nrm[1] = sqrtf(fmaxf(b, 1e-6f));
  }
  __syncthreads();
  if (tid < 128){
    g_ws[OFF_LB + 0*128 + tid] = 1.0f/sqrtf(128.0f);
    g_ws[OFF_LB + 1*128 + tid] = p1s[tid]/nrm[0];
    g_ws[OFF_LB + 2*128 + tid] = p2s[tid]/nrm[1];
  }
  // ---- QR of A = W_proj^T (512 x 8), wave 0, LAPACK sgeqrf+sorgqr convention ----
  if (tid < 64){
    int l = tid;
    float A[8][8], Q[8][8], tau[8];
    #pragma unroll
    for (int c = 0; c < 8; c++)
      #pragma unroll
      for (int p = 0; p < 8; p++)
        A[c][p] = Wp[c*512 + p*64 + l];   // row = p*64+l
    #pragma unroll
    for (int j = 0; j < 8; j++){
      float alpha = __shfl(A[j][0], j, 64);
      float ssq = 0.0f;
      #pragma unroll
      for (int p = 0; p < 8; p++){
        bool live = (p > 0) || (l > j);
        float v = A[j][p];
        ssq += live ? v*v : 0.0f;
      }
      ssq = wred64(ssq);
      float tj, scale;
      if (ssq == 0.0f){ tj = 0.0f; scale = 0.0f; }
      else {
        float bta = -copysignf(sqrtf(alpha*alpha + ssq), alpha);
        tj = (bta - alpha)/bta;
        scale = 1.0f/(alpha - bta);
      }
      tau[j] = tj;
      #pragma unroll
      for (int p = 0; p < 8; p++){
        int row = p*64 + l;
        float v = A[j][p]*scale;
        A[j][p] = (row < j) ? 0.0f : (row == j ? 1.0f : v);
      }
      #pragma unroll
      for (int c = j+1; c < 8; c++){
        float d = 0.0f;
        #pragma unroll
        for (int p = 0; p < 8; p++) d += A[c][p]*A[j][p];
        d = wred64(d)*tj;
        #pragma unroll
        for (int p = 0; p < 8; p++) A[c][p] -= d*A[j][p];
      }
    }
    #pragma unroll
    for (int c = 0; c < 8; c++)
      #pragma unroll
      for (int p = 0; p < 8; p++)
        Q[c][p] = (p == 0 && l == c) ? 1.0f : 0.0f;
    #pragma unroll
    for (int j = 7; j >= 0; j--){
      #pragma unroll
      for (int c = 0; c < 8; c++){
        float d = 0.0f;
        #pragma unroll
        for (int p = 0; p < 8; p++) d += Q[c][p]*A[j][p];
        d = wred64(d)*tau[j];
        #pragma unroll
        for (int p = 0; p < 8; p++) Q[c][p] -= d*A[j][p];
      }
    }
    #pragma unroll
    for (int c = 0; c < 8; c++)
      #pragma unroll
      for (int p = 0; p < 8; p++)
        g_ws[OFF_U + c*512 + p*64 + l] = Q[c][p];   // buf[c][d] = Q[d][c]
  }
}

// ---------------- K2: v = (x . W_eff^T) * vm, transposed store; den partials --------
__global__ __launch_bounds__(256) void k2_proj(const float* __restrict__ x,
                                               const float* __restrict__ vmask){
  int tid = threadIdx.x;
  int l = tid & 63, wv = tid >> 6;
  int g = blockIdx.x*4 + wv;           // wave id 0..4095, 8 rows each
  __shared__ float denw[4];
  float u[8][8];
  #pragma unroll
  for (int k = 0; k < 8; k++)
    #pragma unroll
    for (int e = 0; e < 8; e++)
      u[k][e] = g_ws[OFF_U + k*512 + l*8 + e];
  float denpart = 0.0f;
  for (int rr = 0; rr < 8; rr++){
    int row = g*8 + rr;
    const float* xr = x + (size_t)row*512 + l*8;
    float4 xa = *(const float4*)xr;
    float4 xb = *(const float4*)(xr + 4);
    float xe[8] = {xa.x, xa.y, xa.z, xa.w, xb.x, xb.y, xb.z, xb.w};
    float acc[8];
    float sq = 0.0f;
    #pragma unroll
    for (int k = 0; k < 8; k++){
      float a = 0.0f;
      #pragma unroll
      for (int e = 0; e < 8; e++) a += xe[e]*u[k][e];
      acc[k] = a;
    }
    #pragma unroll
    for (int e = 0; e < 8; e++) sq += xe[e]*xe[e];
    #pragma unroll
    for (int k = 0; k < 8; k++) acc[k] = wred64(acc[k]);
    sq = wred64(sq);
    if (l == 0){
      float vm = vmask[row];
      int b = row >> 14, t = (row >> 7) & 127, n = row & 127;
      int bn = b*128 + n;
      float* vg = g_ws + OFF_V + bn*1024 + t;
      #pragma unroll
      for (int k = 0; k < 8; k++) vg[k*128] = acc[k]*vm;
      denpart += sqrtf(sq);
    }
  }
  if (l == 0) denw[wv] = denpart;
  __syncthreads();
  if (tid == 0) g_ws[OFF_DENP + blockIdx.x] = denw[0]+denw[1]+denw[2]+denw[3];
}

// ---------------- K3: sort + isotonic soft-sort + quantiles + legendre coeffs -------
__global__ __launch_bounds__(256) void k3_sortfeat(){
  int tid = threadIdx.x;
  int l = tid & 63, wv = tid >> 6;
  int rho = blockIdx.x*4 + wv;         // 0..2047 = bn*8 + k
  __shared__ float orig[4][128], srt[4][128], Bl[384];
  __shared__ float pS[4][128];
  __shared__ int   pC[4][128];
  for (int i = tid; i < 384; i += 256) Bl[i] = g_ws[OFF_LB + i];
  const float* vr = g_ws + OFF_V + rho*128;
  orig[wv][2*l]   = vr[2*l];
  orig[wv][2*l+1] = vr[2*l+1];
  srt[wv][2*l] = 0.0f; srt[wv][2*l+1] = 0.0f;
  __syncthreads();
  float c0, c1, c2;
  {
    float a = orig[wv][2*l], b = orig[wv][2*l+1];
    c0 = a*Bl[2*l]       + b*Bl[2*l+1];
    c1 = a*Bl[128+2*l]   + b*Bl[128+2*l+1];
    c2 = a*Bl[256+2*l]   + b*Bl[256+2*l+1];
  }
  c0 = wred64(c0); c1 = wred64(c1); c2 = wred64(c2);
  // rank sort (stable ascending)
  float e0 = orig[wv][2*l], e1 = orig[wv][2*l+1];
  int r0 = 0, r1 = 0;
  for (int j = 0; j < 128; j++){
    float vj = orig[wv][j];
    r0 += (vj < e0) || (vj == e0 && j < 2*l);
    r1 += (vj < e1) || (vj == e1 && j < 2*l+1);
  }
  srt[wv][r0] = e0;
  srt[wv][r1] = e1;
  __syncthreads();
  const float rinv = 22.627416997969522f;  // 1/reg, reg = 0.5*128^-0.5
  bool v0 = (srt[wv][2*l+1] - srt[wv][2*l] > rinv);
  bool v1 = (2*l + 2 < 128) ? (srt[wv][2*l+2] - srt[wv][2*l+1] > rinv) : false;
  if (__any(v0 || v1)){
    if (l == 0){
      int top = -1;
      for (int i = 0; i < 128; i++){
        float y = (float)(128 - i)*rinv + srt[wv][i];
        top++; pS[wv][top] = y; pC[wv][top] = 1;
        while (top > 0 &&
               pS[wv][top]*(float)pC[wv][top-1] > pS[wv][top-1]*(float)pC[wv][top]){
          pS[wv][top-1] += pS[wv][top];
          pC[wv][top-1] += pC[wv][top];
          top--;
        }
      }
      int i = 0;
      for (int blk = 0; blk <= top; blk++){
        float m = pS[wv][blk]/(float)pC[wv][blk];
        for (int c = 0; c < pC[wv][blk]; c++){
          srt[wv][i] = m - (float)(128 - i)*rinv;
          i++;
        }
      }
    }
  }
  if (l == 0){
    int bn = rho >> 3, k = rho & 7;
    float* fb = g_ws + OFF_FEATS + bn*48 + k*6;
    float w0 = 0.1f*127.0f - 12.0f;
    float w1 = 0.5f*127.0f - 63.0f;
    float w2 = 0.9f*127.0f - 114.0f;
    fb[0] = (1.0f - w0)*srt[wv][12]  + w0*srt[wv][13];
    fb[1] = (1.0f - w1)*srt[wv][63]  + w1*srt[wv][64];
    fb[2] = (1.0f - w2)*srt[wv][114] + w2*srt[wv][115];
    fb[3] = c0; fb[4] = c1; fb[5] = c2;
  }
}

// ---------------- K4: per-feature MLP head -> y and per-f energy partials ----------
__global__ __launch_bounds__(256) void k4_head(const float* __restrict__ W1,
                                               const float* __restrict__ b1,
                                               const float* __restrict__ W2){
  int tid = threadIdx.x;
  int ct = blockIdx.x;                  // 0..3 (coltile of 128)
  int rt = blockIdx.y;                  // 0..31 (rowtile of 8 points)
  int cbase = ct*128, rbase = rt*8;
  int cq = tid & 31, r = tid >> 5;      // 32 col-quads x 8 rows
  int c = cbase + cq*4;
  __shared__ float fl[8*48];
  __shared__ float hl[8*768];
  __shared__ float sqlds[4][48];
  for (int i = tid; i < 384; i += 256) fl[i] = g_ws[OFF_FEATS + rbase*48 + i];
  __syncthreads();
  for (int off = tid; off < 6144; off += 256){
    int pr = off/768, k = off%768;
    int f = k >> 4;
    float a = fl[pr*48 + f]*W1[k] + b1[k];
    hl[off] = 0.5f*a*(1.0f + erff(a*0.70710678118654752f));  // exact GELU
  }
  __syncthreads();
  float4 b2v = *(const float4*)(g_ws + OFF_B2 + c);
  float yx = 0, yy = 0, yz = 0, yw = 0;
  int wvid = tid >> 6;
  for (int f = 0; f < 48; f++){
    float px = 0, py = 0, pz = 0, pw = 0;
    #pragma unroll
    for (int w = 0; w < 16; w++){
      int k = f*16 + w;
      float4 w2 = *(const float4*)(W2 + (size_t)k*512 + c);
      float hm = hl[r*768 + k];
      px += hm*w2.x; py += hm*w2.y; pz += hm*w2.z; pw += hm*w2.w;
    }
    yx += px; yy += py; yz += pz; yw += pw;
    float s = px*px*b2v.x + py*py*b2v.y + pz*pz*b2v.z + pw*pw*b2v.w;
    s = wred64(s);
    if ((tid & 63) == 0) sqlds[wvid][f] = s;
  }
  float* yg = g_ws + OFF_Y + (rbase + r)*512 + c;
  float4 yo; yo.x = yx; yo.y = yy; yo.z = yz; yo.w = yw;
  *(float4*)yg = yo;
  __syncthreads();
  if (tid < 48){
    float s = sqlds[0][tid] + sqlds[1][tid] + sqlds[2][tid] + sqlds[3][tid];
    g_ws[OFF_SQP + (rt*4 + ct)*48 + tid] = s;
  }
}

// ---------------- K5n: ||beta_eff * y|| partials --------------------------------
__global__ __launch_bounds__(256) void k5n_num(){
  int tid = threadIdx.x;
  int l = tid & 63, wv = tid >> 6;
  int p = blockIdx.x*4 + wv;            // 0..255
  __shared__ float nw[4];
  float s = 0.0f;
  #pragma unroll
  for (int e = 0; e < 8; e++){
    int d = e*64 + l;
    float by = g_ws[OFF_BEFF + d]*g_ws[OFF_Y + p*512 + d];
    s += by*by;
  }
  s = wred64(s);
  if (l == 0) nw[wv] = sqrtf(s);
  __syncthreads();
  if (tid == 0) g_ws[OFF_NUMP + blockIdx.x] = nw[0]+nw[1]+nw[2]+nw[3];
}

// ---------------- K6: finalize r and r_feat (f32 out) -------------------------------
__global__ __launch_bounds__(256) void k6_fin(float* __restrict__ outt){
  __shared__ float red[256];
  __shared__ float en[96];
  __shared__ float scal[2];
  int tid = threadIdx.x;
  float dp = 0.0f;
  for (int i = tid; i < 1024; i += 256) dp += g_ws[OFF_DENP + i];
  red[tid] = dp; __syncthreads();
  for (int s = 128; s > 0; s >>= 1){
    if (tid < s) red[tid] += red[tid + s];
    __syncthreads();
  }
  if (tid == 0) scal[0] = fmaxf(red[0]/32768.0f, 1e-9f);
  __syncthreads();
  float np_ = (tid < 64) ? g_ws[OFF_NUMP + tid] : 0.0f;
  red[tid] = np_; __syncthreads();
  for (int s = 128; s > 0; s >>= 1){
    if (tid < s) red[tid] += red[tid + s];
    __syncthreads();
  }
  if (tid == 0) scal[1] = red[0]/256.0f;
  __syncthreads();
  float den = scal[0];
  if (tid < 96){
    int b = tid/48, f = tid%48;
    float s = 0.0f;
    for (int j = 0; j < 64; j++) s += g_ws[OFF_SQP + (b*64 + j)*48 + f];
    en[tid] = sqrtf(128.0f*s);
  }
  __syncthreads();
  if (tid == 0) outt[16777216] = scal[1]/den;
  if (tid < 48) outt[16777217 + tid] = 0.5f*(en[tid] + en[48 + tid])/den;
}

// ---------------- K7: h = x + vm * beta_eff * y (f32 out) ----------------------
__global__ __launch_bounds__(256) void k7_out(const float* __restrict__ x,
                                              const float* __restrict__ vmask,
                                              float* __restrict__ outt){
  int q = blockIdx.x*256 + threadIdx.x;  // quad id < 4194304
  size_t fl = (size_t)q*4;
  int d = (int)(fl & 511);
  int row = (int)(fl >> 9);
  int b = row >> 14, n = row & 127;
  int bn = b*128 + n;
  float vm = vmask[row];
  float4 xv = *(const float4*)(x + fl);
  float4 yv = *(const float4*)(g_ws + OFF_Y + bn*512 + d);
  float4 bv = *(const float4*)(g_ws + OFF_BEFF + d);
  float4 o;
  o.x = xv.x + vm*bv.x*yv.x;
  o.y = xv.y + vm*bv.y*yv.y;
  o.z = xv.z + vm*bv.z*yv.z;
  o.w = xv.w + vm*bv.w*yv.w;
  *(float4*)(outt + fl) = o;
}

extern "C" void kernel_launch(void* const* d_in, const int* in_sizes, int n_in,
                              void* d_out, int out_size, void* d_ws, size_t ws_size,
                              hipStream_t stream){
  (void)out_size; (void)d_ws; (void)ws_size;
  const float *x=nullptr,*vm=nullptr,*Wp=nullptr,*W1=nullptr,*b1=nullptr,*W2=nullptr,*beta=nullptr;
  for (int i = 0; i < n_in; i++){
    int s = in_sizes[i];
    const float* p = (const float*)d_in[i];
    if      (s == 16777216) x = p;
    else if (s == 32768)    vm = p;
    else if (s == 4096)     Wp = p;
    else if (s == 393216)   W2 = p;
    else if (s == 512)      beta = p;
    else if (s == 768)      { if (!W1) W1 = p; else b1 = p; }
  }
  float* out = (float*)d_out;

  k1_prep<<<1, 256, 0, stream>>>(Wp, beta);
  k2_proj<<<1024, 256, 0, stream>>>(x, vm);
  k3_sortfeat<<<512, 256, 0, stream>>>();
  k4_head<<<dim3(4, 32), 256, 0, stream>>>(W1, b1, W2);
  k5n_num<<<64, 256, 0, stream>>>();
  k6_fin<<<1, 256, 0, stream>>>(out);
  k7_out<<<16384, 256, 0, stream>>>(x, vm, out);
}

// Round 9
// 114.610 us; speedup vs baseline: 1.4587x; 1.0190x over previous
//
#include <hip/hip_runtime.h>
#include <hip/hip_bf16.h>
#include <math.h>

// All scratch in module-owned device memory (d_ws unused).
// Layout (floats):
#define OFF_BEFF  0        // 512
#define OFF_B2    512      // 512
#define OFF_LB    1024     // 384
#define OFF_U     1408     // 4096 (buf[k][d] = W_eff[k][d] = Q[d][k])
#define OFF_FEATS 5504     // 256*48 = 12288
#define OFF_DENP  17792    // 1024
#define OFF_NUMP  18816    // 256
#define OFF_SQP   19072    // 256*48 = 12288
#define OFF_V     31360    // 256*8*128 = 262144  [bn][k][t]
#define OFF_Y     293504   // 256*512 = 131072   [bn][d]
#define WS_TOTAL  424576   // 1.70 MB

__device__ __align__(16) float g_ws[WS_TOTAL];

static __device__ __forceinline__ float wred64(float v){
  #pragma unroll
  for (int m = 32; m >= 1; m >>= 1) v += __shfl_xor(v, m, 64);
  return v;
}

// ---------------- K1: QR (LAPACK Householder), sigmoid(beta), Legendre basis --------
__global__ __launch_bounds__(256) void k1_prep(const float* __restrict__ Wp,
                                               const float* __restrict__ beta){
  int tid = threadIdx.x;
  __shared__ float p1s[128], p2s[128], nrm[2];
  for (int d = tid; d < 512; d += 256){
    float b = beta[d];
    float s = 1.0f/(1.0f + expf(-b));
    g_ws[OFF_BEFF + d] = s;
    g_ws[OFF_B2 + d] = s*s;
  }
  if (tid < 128){
    float t = -1.0f + 2.0f*(float)tid/127.0f;
    p1s[tid] = t;
    p2s[tid] = 0.5f*(3.0f*t*t - 1.0f);
  }
  __syncthreads();
  if (tid == 0){
    float a = 0, b = 0;
    for (int i = 0; i < 128; i++){ a += p1s[i]*p1s[i]; b += p2s[i]*p2s[i]; }
    nrm[0] = sqrtf(fmaxf(a, 1e-6f));
    nrm[1] = sqrtf(fmaxf(b, 1e-6f));
  }
  __syncthreads();
  if (tid < 128){
    g_ws[OFF_LB + 0*128 + tid] = 1.0f/sqrtf(128.0f);
    g_ws[OFF_LB + 1*128 + tid] = p1s[tid]/nrm[0];
    g_ws[OFF_LB + 2*128 + tid] = p2s[tid]/nrm[1];
  }
  // ---- QR of A = W_proj^T (512 x 8), wave 0, LAPACK sgeqrf+sorgqr convention ----
  if (tid < 64){
    int l = tid;
    float A[8][8], Q[8][8], tau[8];
    #pragma unroll
    for (int c = 0; c < 8; c++)
      #pragma unroll
      for (int p = 0; p < 8; p++)
        A[c][p] = Wp[c*512 + p*64 + l];   // row = p*64+l
    #pragma unroll
    for (int j = 0; j < 8; j++){
      float alpha = __shfl(A[j][0], j, 64);
      float ssq = 0.0f;
      #pragma unroll
      for (int p = 0; p < 8; p++){
        bool live = (p > 0) || (l > j);
        float v = A[j][p];
        ssq += live ? v*v : 0.0f;
      }
      ssq = wred64(ssq);
      float tj, scale;
      if (ssq == 0.0f){ tj = 0.0f; scale = 0.0f; }
      else {
        float bta = -copysignf(sqrtf(alpha*alpha + ssq), alpha);
        tj = (bta - alpha)/bta;
        scale = 1.0f/(alpha - bta);
      }
      tau[j] = tj;
      #pragma unroll
      for (int p = 0; p < 8; p++){
        int row = p*64 + l;
        float v = A[j][p]*scale;
        A[j][p] = (row < j) ? 0.0f : (row == j ? 1.0f : v);
      }
      #pragma unroll
      for (int c = j+1; c < 8; c++){
        float d = 0.0f;
        #pragma unroll
        for (int p = 0; p < 8; p++) d += A[c][p]*A[j][p];
        d = wred64(d)*tj;
        #pragma unroll
        for (int p = 0; p < 8; p++) A[c][p] -= d*A[j][p];
      }
    }
    #pragma unroll
    for (int c = 0; c < 8; c++)
      #pragma unroll
      for (int p = 0; p < 8; p++)
        Q[c][p] = (p == 0 && l == c) ? 1.0f : 0.0f;
    #pragma unroll
    for (int j = 7; j >= 0; j--){
      #pragma unroll
      for (int c = 0; c < 8; c++){
        float d = 0.0f;
        #pragma unroll
        for (int p = 0; p < 8; p++) d += Q[c][p]*A[j][p];
        d = wred64(d)*tau[j];
        #pragma unroll
        for (int p = 0; p < 8; p++) Q[c][p] -= d*A[j][p];
      }
    }
    #pragma unroll
    for (int c = 0; c < 8; c++)
      #pragma unroll
      for (int p = 0; p < 8; p++)
        g_ws[OFF_U + c*512 + p*64 + l] = Q[c][p];   // buf[c][d] = Q[d][c]
  }
}

// ---------------- K2: v = (x . W_eff^T) * vm, transposed store; den partials --------
__global__ __launch_bounds__(256) void k2_proj(const float* __restrict__ x,
                                               const float* __restrict__ vmask){
  int tid = threadIdx.x;
  int l = tid & 63, wv = tid >> 6;
  int g = blockIdx.x*4 + wv;           // wave id 0..4095, 8 rows each
  __shared__ float denw[4];
  float u[8][8];
  #pragma unroll
  for (int k = 0; k < 8; k++)
    #pragma unroll
    for (int e = 0; e < 8; e++)
      u[k][e] = g_ws[OFF_U + k*512 + l*8 + e];
  float denpart = 0.0f;
  for (int rr = 0; rr < 8; rr++){
    int row = g*8 + rr;
    const float* xr = x + (size_t)row*512 + l*8;
    float4 xa = *(const float4*)xr;
    float4 xb = *(const float4*)(xr + 4);
    float xe[8] = {xa.x, xa.y, xa.z, xa.w, xb.x, xb.y, xb.z, xb.w};
    float acc[8];
    float sq = 0.0f;
    #pragma unroll
    for (int k = 0; k < 8; k++){
      float a = 0.0f;
      #pragma unroll
      for (int e = 0; e < 8; e++) a += xe[e]*u[k][e];
      acc[k] = a;
    }
    #pragma unroll
    for (int e = 0; e < 8; e++) sq += xe[e]*xe[e];
    #pragma unroll
    for (int k = 0; k < 8; k++) acc[k] = wred64(acc[k]);
    sq = wred64(sq);
    if (l == 0){
      float vm = vmask[row];
      int b = row >> 14, t = (row >> 7) & 127, n = row & 127;
      int bn = b*128 + n;
      float* vg = g_ws + OFF_V + bn*1024 + t;
      #pragma unroll
      for (int k = 0; k < 8; k++) vg[k*128] = acc[k]*vm;
      denpart += sqrtf(sq);
    }
  }
  if (l == 0) denw[wv] = denpart;
  __syncthreads();
  if (tid == 0) g_ws[OFF_DENP + blockIdx.x] = denw[0]+denw[1]+denw[2]+denw[3];
}

// ---------------- K3: sort + isotonic soft-sort + quantiles + legendre coeffs -------
__global__ __launch_bounds__(256) void k3_sortfeat(){
  int tid = threadIdx.x;
  int l = tid & 63, wv = tid >> 6;
  int rho = blockIdx.x*4 + wv;         // 0..2047 = bn*8 + k
  __shared__ float orig[4][128], srt[4][128], Bl[384];
  __shared__ float pS[4][128];
  __shared__ int   pC[4][128];
  for (int i = tid; i < 384; i += 256) Bl[i] = g_ws[OFF_LB + i];
  const float* vr = g_ws + OFF_V + rho*128;
  orig[wv][2*l]   = vr[2*l];
  orig[wv][2*l+1] = vr[2*l+1];
  srt[wv][2*l] = 0.0f; srt[wv][2*l+1] = 0.0f;
  __syncthreads();
  float c0, c1, c2;
  {
    float a = orig[wv][2*l], b = orig[wv][2*l+1];
    c0 = a*Bl[2*l]       + b*Bl[2*l+1];
    c1 = a*Bl[128+2*l]   + b*Bl[128+2*l+1];
    c2 = a*Bl[256+2*l]   + b*Bl[256+2*l+1];
  }
  c0 = wred64(c0); c1 = wred64(c1); c2 = wred64(c2);
  // rank sort (stable ascending)
  float e0 = orig[wv][2*l], e1 = orig[wv][2*l+1];
  int r0 = 0, r1 = 0;
  for (int j = 0; j < 128; j++){
    float vj = orig[wv][j];
    r0 += (vj < e0) || (vj == e0 && j < 2*l);
    r1 += (vj < e1) || (vj == e1 && j < 2*l+1);
  }
  srt[wv][r0] = e0;
  srt[wv][r1] = e1;
  __syncthreads();
  const float rinv = 22.627416997969522f;  // 1/reg, reg = 0.5*128^-0.5
  bool v0 = (srt[wv][2*l+1] - srt[wv][2*l] > rinv);
  bool v1 = (2*l + 2 < 128) ? (srt[wv][2*l+2] - srt[wv][2*l+1] > rinv) : false;
  if (__any(v0 || v1)){
    if (l == 0){
      int top = -1;
      for (int i = 0; i < 128; i++){
        float y = (float)(128 - i)*rinv + srt[wv][i];
        top++; pS[wv][top] = y; pC[wv][top] = 1;
        while (top > 0 &&
               pS[wv][top]*(float)pC[wv][top-1] > pS[wv][top-1]*(float)pC[wv][top]){
          pS[wv][top-1] += pS[wv][top];
          pC[wv][top-1] += pC[wv][top];
          top--;
        }
      }
      int i = 0;
      for (int blk = 0; blk <= top; blk++){
        float m = pS[wv][blk]/(float)pC[wv][blk];
        for (int c = 0; c < pC[wv][blk]; c++){
          srt[wv][i] = m - (float)(128 - i)*rinv;
          i++;
        }
      }
    }
  }
  if (l == 0){
    int bn = rho >> 3, k = rho & 7;
    float* fb = g_ws + OFF_FEATS + bn*48 + k*6;
    float w0 = 0.1f*127.0f - 12.0f;
    float w1 = 0.5f*127.0f - 63.0f;
    float w2 = 0.9f*127.0f - 114.0f;
    fb[0] = (1.0f - w0)*srt[wv][12]  + w0*srt[wv][13];
    fb[1] = (1.0f - w1)*srt[wv][63]  + w1*srt[wv][64];
    fb[2] = (1.0f - w2)*srt[wv][114] + w2*srt[wv][115];
    fb[3] = c0; fb[4] = c1; fb[5] = c2;
  }
}

// ---------------- K4: per-bn MLP head -> y, energy partials, num partial ------------
// One block per bn, 512 threads = one per d. W2 reads coalesced; hl broadcast.
__global__ __launch_bounds__(512) void k4_head(const float* __restrict__ W1,
                                               const float* __restrict__ b1,
                                               const float* __restrict__ W2){
  int bn = blockIdx.x;                  // 0..255
  int tid = threadIdx.x;                // 0..511 = d
  int l = tid & 63, wv = tid >> 6;      // 8 waves
  __shared__ float fl[48];
  __shared__ float hl[768];
  __shared__ float sqlds[8][48];
  __shared__ float nw[8];
  if (tid < 48) fl[tid] = g_ws[OFF_FEATS + bn*48 + tid];
  __syncthreads();
  for (int off = tid; off < 768; off += 512){
    int f = off >> 4;
    float a = fl[f]*W1[off] + b1[off];
    hl[off] = 0.5f*a*(1.0f + erff(a*0.70710678118654752f));  // exact GELU
  }
  __syncthreads();
  int d = tid;
  float be = g_ws[OFF_BEFF + d];
  float b2 = be*be;
  float y = 0.0f;
  for (int f = 0; f < 48; f++){
    float p = 0.0f;
    #pragma unroll
    for (int w = 0; w < 16; w++){
      p += hl[f*16 + w] * W2[(size_t)(f*16 + w)*512 + d];
    }
    y += p;
    float e = wred64(p*p*b2);
    if (l == 0) sqlds[wv][f] = e;
  }
  g_ws[OFF_Y + bn*512 + d] = y;
  float ns = wred64(y*y*b2);
  if (l == 0) nw[wv] = ns;
  __syncthreads();
  if (tid < 48){
    float s = 0.0f;
    #pragma unroll
    for (int w = 0; w < 8; w++) s += sqlds[w][tid];
    g_ws[OFF_SQP + bn*48 + tid] = s;
  }
  if (tid == 0){
    float s = nw[0]+nw[1]+nw[2]+nw[3]+nw[4]+nw[5]+nw[6]+nw[7];
    g_ws[OFF_NUMP + bn] = sqrtf(s);
  }
}

// ---------------- K6: finalize r and r_feat (f32 out) -------------------------------
__global__ __launch_bounds__(256) void k6_fin(float* __restrict__ outt){
  __shared__ float red[256];
  __shared__ float en[96];
  __shared__ float scal[2];
  int tid = threadIdx.x;
  float dp = 0.0f;
  for (int i = tid; i < 1024; i += 256) dp += g_ws[OFF_DENP + i];
  red[tid] = dp; __syncthreads();
  for (int s = 128; s > 0; s >>= 1){
    if (tid < s) red[tid] += red[tid + s];
    __syncthreads();
  }
  if (tid == 0) scal[0] = fmaxf(red[0]/32768.0f, 1e-9f);
  __syncthreads();
  red[tid] = g_ws[OFF_NUMP + tid];
  __syncthreads();
  for (int s = 128; s > 0; s >>= 1){
    if (tid < s) red[tid] += red[tid + s];
    __syncthreads();
  }
  if (tid == 0) scal[1] = red[0]/256.0f;
  __syncthreads();
  float den = scal[0];
  if (tid < 96){
    int b = tid/48, f = tid%48;
    float s = 0.0f;
    for (int j = 0; j < 128; j++) s += g_ws[OFF_SQP + (b*128 + j)*48 + f];
    en[tid] = sqrtf(128.0f*s);
  }
  __syncthreads();
  if (tid == 0) outt[16777216] = scal[1]/den;
  if (tid < 48) outt[16777217 + tid] = 0.5f*(en[tid] + en[48 + tid])/den;
}

// ---------------- K7: h = x + vm * beta_eff * y (f32 out) ----------------------
__global__ __launch_bounds__(256) void k7_out(const float* __restrict__ x,
                                              const float* __restrict__ vmask,
                                              float* __restrict__ outt){
  int q = blockIdx.x*256 + threadIdx.x;  // quad id < 4194304
  size_t fl = (size_t)q*4;
  int d = (int)(fl & 511);
  int row = (int)(fl >> 9);
  int b = row >> 14, n = row & 127;
  int bn = b*128 + n;
  float vm = vmask[row];
  float4 xv = *(const float4*)(x + fl);
  float4 yv = *(const float4*)(g_ws + OFF_Y + bn*512 + d);
  float4 bv = *(const float4*)(g_ws + OFF_BEFF + d);
  float4 o;
  o.x = xv.x + vm*bv.x*yv.x;
  o.y = xv.y + vm*bv.y*yv.y;
  o.z = xv.z + vm*bv.z*yv.z;
  o.w = xv.w + vm*bv.w*yv.w;
  *(float4*)(outt + fl) = o;
}

extern "C" void kernel_launch(void* const* d_in, const int* in_sizes, int n_in,
                              void* d_out, int out_size, void* d_ws, size_t ws_size,
                              hipStream_t stream){
  (void)out_size; (void)d_ws; (void)ws_size;
  const float *x=nullptr,*vm=nullptr,*Wp=nullptr,*W1=nullptr,*b1=nullptr,*W2=nullptr,*beta=nullptr;
  for (int i = 0; i < n_in; i++){
    int s = in_sizes[i];
    const float* p = (const float*)d_in[i];
    if      (s == 16777216) x = p;
    else if (s == 32768)    vm = p;
    else if (s == 4096)     Wp = p;
    else if (s == 393216)   W2 = p;
    else if (s == 512)      beta = p;
    else if (s == 768)      { if (!W1) W1 = p; else b1 = p; }
  }
  float* out = (float*)d_out;

  k1_prep<<<1, 256, 0, stream>>>(Wp, beta);
  k2_proj<<<1024, 256, 0, stream>>>(x, vm);
  k3_sortfeat<<<512, 256, 0, stream>>>();
  k4_head<<<256, 512, 0, stream>>>(W1, b1, W2);
  k6_fin<<<1, 256, 0, stream>>>(out);
  k7_out<<<16384, 256, 0, stream>>>(x, vm, out);
}

// Round 10
// 99.056 us; speedup vs baseline: 1.6878x; 1.1570x over previous
//
#include <hip/hip_runtime.h>
#include <hip/hip_bf16.h>
#include <math.h>

// All scratch in module-owned device memory (d_ws unused).
// Layout (floats):
#define OFF_BEFF  0        // 512
#define OFF_B2    512      // 512
#define OFF_LB    1024     // 384
#define OFF_U     1408     // 4096 (buf[k][d] = W_eff[k][d] = Q[d][k])
#define OFF_FEATS 5504     // 256*48 = 12288
#define OFF_DENP  17792    // 1024
#define OFF_NUMP  18816    // 256
#define OFF_SQP   19072    // 256*48 = 12288
#define OFF_V     31360    // 256*8*128 = 262144  [bn][k][t]
#define OFF_Y     293504   // 256*512 = 131072   [bn][d]
#define OFF_YP    424576   // 256*8*512 = 1048576 [bn][slice][d]
#define WS_TOTAL  1473152  // 5.9 MB

__device__ __align__(16) float g_ws[WS_TOTAL];

static __device__ __forceinline__ float wred64(float v){
  #pragma unroll
  for (int m = 32; m >= 1; m >>= 1) v += __shfl_xor(v, m, 64);
  return v;
}

// ---------------- K1: QR (LAPACK Householder), sigmoid(beta), Legendre basis --------
__global__ __launch_bounds__(256) void k1_prep(const float* __restrict__ Wp,
                                               const float* __restrict__ beta){
  int tid = threadIdx.x;
  __shared__ float p1s[128], p2s[128], nrm[2];
  for (int d = tid; d < 512; d += 256){
    float b = beta[d];
    float s = 1.0f/(1.0f + expf(-b));
    g_ws[OFF_BEFF + d] = s;
    g_ws[OFF_B2 + d] = s*s;
  }
  if (tid < 128){
    float t = -1.0f + 2.0f*(float)tid/127.0f;
    p1s[tid] = t;
    p2s[tid] = 0.5f*(3.0f*t*t - 1.0f);
  }
  __syncthreads();
  if (tid == 0){
    float a = 0, b = 0;
    for (int i = 0; i < 128; i++){ a += p1s[i]*p1s[i]; b += p2s[i]*p2s[i]; }
    nrm[0] = sqrtf(fmaxf(a, 1e-6f));
    nrm[1] = sqrtf(fmaxf(b, 1e-6f));
  }
  __syncthreads();
  if (tid < 128){
    g_ws[OFF_LB + 0*128 + tid] = 1.0f/sqrtf(128.0f);
    g_ws[OFF_LB + 1*128 + tid] = p1s[tid]/nrm[0];
    g_ws[OFF_LB + 2*128 + tid] = p2s[tid]/nrm[1];
  }
  // ---- QR of A = W_proj^T (512 x 8), wave 0, LAPACK sgeqrf+sorgqr convention ----
  if (tid < 64){
    int l = tid;
    float A[8][8], Q[8][8], tau[8];
    #pragma unroll
    for (int c = 0; c < 8; c++)
      #pragma unroll
      for (int p = 0; p < 8; p++)
        A[c][p] = Wp[c*512 + p*64 + l];   // row = p*64+l
    #pragma unroll
    for (int j = 0; j < 8; j++){
      float alpha = __shfl(A[j][0], j, 64);
      float ssq = 0.0f;
      #pragma unroll
      for (int p = 0; p < 8; p++){
        bool live = (p > 0) || (l > j);
        float v = A[j][p];
        ssq += live ? v*v : 0.0f;
      }
      ssq = wred64(ssq);
      float tj, scale;
      if (ssq == 0.0f){ tj = 0.0f; scale = 0.0f; }
      else {
        float bta = -copysignf(sqrtf(alpha*alpha + ssq), alpha);
        tj = (bta - alpha)/bta;
        scale = 1.0f/(alpha - bta);
      }
      tau[j] = tj;
      #pragma unroll
      for (int p = 0; p < 8; p++){
        int row = p*64 + l;
        float v = A[j][p]*scale;
        A[j][p] = (row < j) ? 0.0f : (row == j ? 1.0f : v);
      }
      #pragma unroll
      for (int c = j+1; c < 8; c++){
        float d = 0.0f;
        #pragma unroll
        for (int p = 0; p < 8; p++) d += A[c][p]*A[j][p];
        d = wred64(d)*tj;
        #pragma unroll
        for (int p = 0; p < 8; p++) A[c][p] -= d*A[j][p];
      }
    }
    #pragma unroll
    for (int c = 0; c < 8; c++)
      #pragma unroll
      for (int p = 0; p < 8; p++)
        Q[c][p] = (p == 0 && l == c) ? 1.0f : 0.0f;
    #pragma unroll
    for (int j = 7; j >= 0; j--){
      #pragma unroll
      for (int c = 0; c < 8; c++){
        float d = 0.0f;
        #pragma unroll
        for (int p = 0; p < 8; p++) d += Q[c][p]*A[j][p];
        d = wred64(d)*tau[j];
        #pragma unroll
        for (int p = 0; p < 8; p++) Q[c][p] -= d*A[j][p];
      }
    }
    #pragma unroll
    for (int c = 0; c < 8; c++)
      #pragma unroll
      for (int p = 0; p < 8; p++)
        g_ws[OFF_U + c*512 + p*64 + l] = Q[c][p];   // buf[c][d] = Q[d][c]
  }
}

// ---------------- K2: v = (x . W_eff^T) * vm, transposed store; den partials --------
__global__ __launch_bounds__(256) void k2_proj(const float* __restrict__ x,
                                               const float* __restrict__ vmask){
  int tid = threadIdx.x;
  int l = tid & 63, wv = tid >> 6;
  int g = blockIdx.x*4 + wv;           // wave id 0..4095, 8 rows each
  __shared__ float denw[4];
  float u[8][8];
  #pragma unroll
  for (int k = 0; k < 8; k++)
    #pragma unroll
    for (int e = 0; e < 8; e++)
      u[k][e] = g_ws[OFF_U + k*512 + l*8 + e];
  float denpart = 0.0f;
  for (int rr = 0; rr < 8; rr++){
    int row = g*8 + rr;
    const float* xr = x + (size_t)row*512 + l*8;
    float4 xa = *(const float4*)xr;
    float4 xb = *(const float4*)(xr + 4);
    float xe[8] = {xa.x, xa.y, xa.z, xa.w, xb.x, xb.y, xb.z, xb.w};
    float acc[8];
    float sq = 0.0f;
    #pragma unroll
    for (int k = 0; k < 8; k++){
      float a = 0.0f;
      #pragma unroll
      for (int e = 0; e < 8; e++) a += xe[e]*u[k][e];
      acc[k] = a;
    }
    #pragma unroll
    for (int e = 0; e < 8; e++) sq += xe[e]*xe[e];
    #pragma unroll
    for (int k = 0; k < 8; k++) acc[k] = wred64(acc[k]);
    sq = wred64(sq);
    if (l == 0){
      float vm = vmask[row];
      int b = row >> 14, t = (row >> 7) & 127, n = row & 127;
      int bn = b*128 + n;
      float* vg = g_ws + OFF_V + bn*1024 + t;
      #pragma unroll
      for (int k = 0; k < 8; k++) vg[k*128] = acc[k]*vm;
      denpart += sqrtf(sq);
    }
  }
  if (l == 0) denw[wv] = denpart;
  __syncthreads();
  if (tid == 0) g_ws[OFF_DENP + blockIdx.x] = denw[0]+denw[1]+denw[2]+denw[3];
}

// ---------------- K3: sort + isotonic soft-sort + quantiles + legendre coeffs -------
__global__ __launch_bounds__(256) void k3_sortfeat(){
  int tid = threadIdx.x;
  int l = tid & 63, wv = tid >> 6;
  int rho = blockIdx.x*4 + wv;         // 0..2047 = bn*8 + k
  __shared__ float orig[4][128], srt[4][128], Bl[384];
  __shared__ float pS[4][128];
  __shared__ int   pC[4][128];
  for (int i = tid; i < 384; i += 256) Bl[i] = g_ws[OFF_LB + i];
  const float* vr = g_ws + OFF_V + rho*128;
  orig[wv][2*l]   = vr[2*l];
  orig[wv][2*l+1] = vr[2*l+1];
  srt[wv][2*l] = 0.0f; srt[wv][2*l+1] = 0.0f;
  __syncthreads();
  float c0, c1, c2;
  {
    float a = orig[wv][2*l], b = orig[wv][2*l+1];
    c0 = a*Bl[2*l]       + b*Bl[2*l+1];
    c1 = a*Bl[128+2*l]   + b*Bl[128+2*l+1];
    c2 = a*Bl[256+2*l]   + b*Bl[256+2*l+1];
  }
  c0 = wred64(c0); c1 = wred64(c1); c2 = wred64(c2);
  // rank sort (stable ascending)
  float e0 = orig[wv][2*l], e1 = orig[wv][2*l+1];
  int r0 = 0, r1 = 0;
  for (int j = 0; j < 128; j++){
    float vj = orig[wv][j];
    r0 += (vj < e0) || (vj == e0 && j < 2*l);
    r1 += (vj < e1) || (vj == e1 && j < 2*l+1);
  }
  srt[wv][r0] = e0;
  srt[wv][r1] = e1;
  __syncthreads();
  const float rinv = 22.627416997969522f;  // 1/reg, reg = 0.5*128^-0.5
  bool v0 = (srt[wv][2*l+1] - srt[wv][2*l] > rinv);
  bool v1 = (2*l + 2 < 128) ? (srt[wv][2*l+2] - srt[wv][2*l+1] > rinv) : false;
  if (__any(v0 || v1)){
    if (l == 0){
      int top = -1;
      for (int i = 0; i < 128; i++){
        float y = (float)(128 - i)*rinv + srt[wv][i];
        top++; pS[wv][top] = y; pC[wv][top] = 1;
        while (top > 0 &&
               pS[wv][top]*(float)pC[wv][top-1] > pS[wv][top-1]*(float)pC[wv][top]){
          pS[wv][top-1] += pS[wv][top];
          pC[wv][top-1] += pC[wv][top];
          top--;
        }
      }
      int i = 0;
      for (int blk = 0; blk <= top; blk++){
        float m = pS[wv][blk]/(float)pC[wv][blk];
        for (int c = 0; c < pC[wv][blk]; c++){
          srt[wv][i] = m - (float)(128 - i)*rinv;
          i++;
        }
      }
    }
  }
  if (l == 0){
    int bn = rho >> 3, k = rho & 7;
    float* fb = g_ws + OFF_FEATS + bn*48 + k*6;
    float w0 = 0.1f*127.0f - 12.0f;
    float w1 = 0.5f*127.0f - 63.0f;
    float w2 = 0.9f*127.0f - 114.0f;
    fb[0] = (1.0f - w0)*srt[wv][12]  + w0*srt[wv][13];
    fb[1] = (1.0f - w1)*srt[wv][63]  + w1*srt[wv][64];
    fb[2] = (1.0f - w2)*srt[wv][114] + w2*srt[wv][115];
    fb[3] = c0; fb[4] = c1; fb[5] = c2;
  }
}

// ---------------- K4a: head partials. Block = (bn-pair, f-slice of 6) ---------------
// 1024 blocks x 512 threads (one per d). 2 bn share each W2 slice read.
__global__ __launch_bounds__(512) void k4a_head(const float* __restrict__ W1,
                                                const float* __restrict__ b1,
                                                const float* __restrict__ W2){
  int blk = blockIdx.x;                 // 0..1023
  int s   = blk & 7;                    // f-slice: f in [s*6, s*6+6)
  int bnp = blk >> 3;                   // 0..127
  int bn0 = bnp*2, bn1 = bn0 + 1;
  int tid = threadIdx.x;                // = d
  int l = tid & 63, wv = tid >> 6;      // 8 waves
  __shared__ float hl0[96], hl1[96];
  __shared__ float sq[8][12];
  if (tid < 192){
    int which = tid >= 96;
    int i = which ? tid - 96 : tid;     // f_local*16 + w
    int f = s*6 + (i >> 4);
    int k = f*16 + (i & 15);
    int bn = which ? bn1 : bn0;
    float a = g_ws[OFF_FEATS + bn*48 + f]*W1[k] + b1[k];
    float g = 0.5f*a*(1.0f + erff(a*0.70710678118654752f));  // exact GELU
    if (which) hl1[i] = g; else hl0[i] = g;
  }
  __syncthreads();
  int d = tid;
  float b2 = g_ws[OFF_B2 + d];
  float y0 = 0.0f, y1 = 0.0f;
  const float* w2base = W2 + (size_t)(s*96)*512 + d;
  #pragma unroll
  for (int fl_ = 0; fl_ < 6; fl_++){
    float p0 = 0.0f, p1 = 0.0f;
    #pragma unroll
    for (int w = 0; w < 16; w++){
      float w2 = w2base[(size_t)(fl_*16 + w)*512];
      p0 += hl0[fl_*16 + w]*w2;
      p1 += hl1[fl_*16 + w]*w2;
    }
    y0 += p0; y1 += p1;
    float e0 = wred64(p0*p0*b2);
    float e1 = wred64(p1*p1*b2);
    if (l == 0){ sq[wv][fl_*2] = e0; sq[wv][fl_*2 + 1] = e1; }
  }
  g_ws[OFF_YP + (size_t)(bn0*8 + s)*512 + d] = y0;
  g_ws[OFF_YP + (size_t)(bn1*8 + s)*512 + d] = y1;
  __syncthreads();
  if (tid < 12){
    float t = 0.0f;
    #pragma unroll
    for (int w = 0; w < 8; w++) t += sq[w][tid];
    int fl_ = tid >> 1, which = tid & 1;
    int bn = which ? bn1 : bn0;
    g_ws[OFF_SQP + bn*48 + s*6 + fl_] = t;
  }
}

// ---------------- K4b: y = sum of slice partials; num per bn ------------------------
__global__ __launch_bounds__(512) void k4b_red(){
  int bn = blockIdx.x;
  int tid = threadIdx.x;
  int l = tid & 63, wv = tid >> 6;
  __shared__ float nw[8];
  float y = 0.0f;
  #pragma unroll
  for (int s = 0; s < 8; s++) y += g_ws[OFF_YP + (size_t)(bn*8 + s)*512 + tid];
  g_ws[OFF_Y + bn*512 + tid] = y;
  float be = g_ws[OFF_BEFF + tid];
  float by = be*y;
  float ns = wred64(by*by);
  if (l == 0) nw[wv] = ns;
  __syncthreads();
  if (tid == 0){
    float s = nw[0]+nw[1]+nw[2]+nw[3]+nw[4]+nw[5]+nw[6]+nw[7];
    g_ws[OFF_NUMP + bn] = sqrtf(s);
  }
}

// ---------------- K6: finalize r and r_feat (f32 out) -------------------------------
__global__ __launch_bounds__(256) void k6_fin(float* __restrict__ outt){
  __shared__ float red[256];
  __shared__ float en[96];
  __shared__ float scal[2];
  int tid = threadIdx.x;
  float dp = 0.0f;
  for (int i = tid; i < 1024; i += 256) dp += g_ws[OFF_DENP + i];
  red[tid] = dp; __syncthreads();
  for (int s = 128; s > 0; s >>= 1){
    if (tid < s) red[tid] += red[tid + s];
    __syncthreads();
  }
  if (tid == 0) scal[0] = fmaxf(red[0]/32768.0f, 1e-9f);
  __syncthreads();
  red[tid] = g_ws[OFF_NUMP + tid];
  __syncthreads();
  for (int s = 128; s > 0; s >>= 1){
    if (tid < s) red[tid] += red[tid + s];
    __syncthreads();
  }
  if (tid == 0) scal[1] = red[0]/256.0f;
  __syncthreads();
  float den = scal[0];
  if (tid < 96){
    int b = tid/48, f = tid%48;
    float s = 0.0f;
    for (int j = 0; j < 128; j++) s += g_ws[OFF_SQP + (b*128 + j)*48 + f];
    en[tid] = sqrtf(128.0f*s);
  }
  __syncthreads();
  if (tid == 0) outt[16777216] = scal[1]/den;
  if (tid < 48) outt[16777217 + tid] = 0.5f*(en[tid] + en[48 + tid])/den;
}

// ---------------- K7: h = x + vm * beta_eff * y (f32 out) ----------------------
__global__ __launch_bounds__(256) void k7_out(const float* __restrict__ x,
                                              const float* __restrict__ vmask,
                                              float* __restrict__ outt){
  int q = blockIdx.x*256 + threadIdx.x;  // quad id < 4194304
  size_t fl = (size_t)q*4;
  int d = (int)(fl & 511);
  int row = (int)(fl >> 9);
  int b = row >> 14, n = row & 127;
  int bn = b*128 + n;
  float vm = vmask[row];
  float4 xv = *(const float4*)(x + fl);
  float4 yv = *(const float4*)(g_ws + OFF_Y + bn*512 + d);
  float4 bv = *(const float4*)(g_ws + OFF_BEFF + d);
  float4 o;
  o.x = xv.x + vm*bv.x*yv.x;
  o.y = xv.y + vm*bv.y*yv.y;
  o.z = xv.z + vm*bv.z*yv.z;
  o.w = xv.w + vm*bv.w*yv.w;
  *(float4*)(outt + fl) = o;
}

extern "C" void kernel_launch(void* const* d_in, const int* in_sizes, int n_in,
                              void* d_out, int out_size, void* d_ws, size_t ws_size,
                              hipStream_t stream){
  (void)out_size; (void)d_ws; (void)ws_size;
  const float *x=nullptr,*vm=nullptr,*Wp=nullptr,*W1=nullptr,*b1=nullptr,*W2=nullptr,*beta=nullptr;
  for (int i = 0; i < n_in; i++){
    int s = in_sizes[i];
    const float* p = (const float*)d_in[i];
    if      (s == 16777216) x = p;
    else if (s == 32768)    vm = p;
    else if (s == 4096)     Wp = p;
    else if (s == 393216)   W2 = p;
    else if (s == 512)      beta = p;
    else if (s == 768)      { if (!W1) W1 = p; else b1 = p; }
  }
  float* out = (float*)d_out;

  k1_prep<<<1, 256, 0, stream>>>(Wp, beta);
  k2_proj<<<1024, 256, 0, stream>>>(x, vm);
  k3_sortfeat<<<512, 256, 0, stream>>>();
  k4a_head<<<1024, 512, 0, stream>>>(W1, b1, W2);
  k4b_red<<<256, 512, 0, stream>>>();
  k6_fin<<<1, 256, 0, stream>>>(out);
  k7_out<<<16384, 256, 0, stream>>>(x, vm, out);
}

// Round 11
// 88.920 us; speedup vs baseline: 1.8801x; 1.1140x over previous
//
#include <hip/hip_runtime.h>
#include <hip/hip_bf16.h>
#include <math.h>

// All scratch in module-owned device memory (d_ws unused).
// Layout (floats):
#define OFF_BEFF  0        // 512
#define OFF_B2    512      // 512
#define OFF_LB    1024     // 384
#define OFF_U     1408     // 4096 (buf[k][d] = W_eff[k][d] = Q[d][k])
#define OFF_FEATS 5504     // 256*48 = 12288
#define OFF_DENP  17792    // 1024
#define OFF_NUMP  18816    // 256
#define OFF_SQP   19072    // 256*48 = 12288
#define OFF_V     31360    // 256*8*128 = 262144  [bn][k][t]
#define OFF_Y     293504   // 256*512 = 131072   [bn][d]
#define OFF_YP    424576   // 256*8*512 = 1048576 [bn][slice][d]
#define WS_TOTAL  1473152  // 5.9 MB

__device__ __align__(16) float g_ws[WS_TOTAL];

static __device__ __forceinline__ float wred64(float v){
  #pragma unroll
  for (int m = 32; m >= 1; m >>= 1) v += __shfl_xor(v, m, 64);
  return v;
}

// ---------------- K1: QR (LAPACK Householder), sigmoid(beta), Legendre basis --------
__global__ __launch_bounds__(256) void k1_prep(const float* __restrict__ Wp,
                                               const float* __restrict__ beta){
  int tid = threadIdx.x;
  __shared__ float p1s[128], p2s[128], nrm[2];
  for (int d = tid; d < 512; d += 256){
    float b = beta[d];
    float s = 1.0f/(1.0f + expf(-b));
    g_ws[OFF_BEFF + d] = s;
    g_ws[OFF_B2 + d] = s*s;
  }
  if (tid < 128){
    float t = -1.0f + 2.0f*(float)tid/127.0f;
    p1s[tid] = t;
    p2s[tid] = 0.5f*(3.0f*t*t - 1.0f);
  }
  __syncthreads();
  if (tid == 0){
    float a = 0, b = 0;
    for (int i = 0; i < 128; i++){ a += p1s[i]*p1s[i]; b += p2s[i]*p2s[i]; }
    nrm[0] = sqrtf(fmaxf(a, 1e-6f));
    nrm[1] = sqrtf(fmaxf(b, 1e-6f));
  }
  __syncthreads();
  if (tid < 128){
    g_ws[OFF_LB + 0*128 + tid] = 1.0f/sqrtf(128.0f);
    g_ws[OFF_LB + 1*128 + tid] = p1s[tid]/nrm[0];
    g_ws[OFF_LB + 2*128 + tid] = p2s[tid]/nrm[1];
  }
  // ---- QR of A = W_proj^T (512 x 8), wave 0, LAPACK sgeqrf+sorgqr convention ----
  if (tid < 64){
    int l = tid;
    float A[8][8], Q[8][8], tau[8];
    #pragma unroll
    for (int c = 0; c < 8; c++)
      #pragma unroll
      for (int p = 0; p < 8; p++)
        A[c][p] = Wp[c*512 + p*64 + l];   // row = p*64+l
    #pragma unroll
    for (int j = 0; j < 8; j++){
      float alpha = __shfl(A[j][0], j, 64);
      float ssq = 0.0f;
      #pragma unroll
      for (int p = 0; p < 8; p++){
        bool live = (p > 0) || (l > j);
        float v = A[j][p];
        ssq += live ? v*v : 0.0f;
      }
      ssq = wred64(ssq);
      float tj, scale;
      if (ssq == 0.0f){ tj = 0.0f; scale = 0.0f; }
      else {
        float bta = -copysignf(sqrtf(alpha*alpha + ssq), alpha);
        tj = (bta - alpha)/bta;
        scale = 1.0f/(alpha - bta);
      }
      tau[j] = tj;
      #pragma unroll
      for (int p = 0; p < 8; p++){
        int row = p*64 + l;
        float v = A[j][p]*scale;
        A[j][p] = (row < j) ? 0.0f : (row == j ? 1.0f : v);
      }
      #pragma unroll
      for (int c = j+1; c < 8; c++){
        float d = 0.0f;
        #pragma unroll
        for (int p = 0; p < 8; p++) d += A[c][p]*A[j][p];
        d = wred64(d)*tj;
        #pragma unroll
        for (int p = 0; p < 8; p++) A[c][p] -= d*A[j][p];
      }
    }
    #pragma unroll
    for (int c = 0; c < 8; c++)
      #pragma unroll
      for (int p = 0; p < 8; p++)
        Q[c][p] = (p == 0 && l == c) ? 1.0f : 0.0f;
    #pragma unroll
    for (int j = 7; j >= 0; j--){
      #pragma unroll
      for (int c = 0; c < 8; c++){
        float d = 0.0f;
        #pragma unroll
        for (int p = 0; p < 8; p++) d += Q[c][p]*A[j][p];
        d = wred64(d)*tau[j];
        #pragma unroll
        for (int p = 0; p < 8; p++) Q[c][p] -= d*A[j][p];
      }
    }
    #pragma unroll
    for (int c = 0; c < 8; c++)
      #pragma unroll
      for (int p = 0; p < 8; p++)
        g_ws[OFF_U + c*512 + p*64 + l] = Q[c][p];   // buf[c][d] = Q[d][c]
  }
}

// ---------------- K2: v = (x . W_eff^T) * vm, transposed store; den partials --------
// Reduce-scatter butterfly: 16 DS ops/row instead of 54.
__global__ __launch_bounds__(256) void k2_proj(const float* __restrict__ x,
                                               const float* __restrict__ vmask){
  int tid = threadIdx.x;
  int l = tid & 63, wv = tid >> 6;
  int g = blockIdx.x*4 + wv;           // wave id 0..4095, 8 rows each
  __shared__ float denw[4];
  float u[8][8];
  #pragma unroll
  for (int k = 0; k < 8; k++)
    #pragma unroll
    for (int e = 0; e < 8; e++)
      u[k][e] = g_ws[OFF_U + k*512 + l*8 + e];
  // lane's output k after reduce-scatter: bit-reverse of (l & 7)
  int kk = ((l & 1) << 2) | (l & 2) | ((l & 4) >> 2);
  float denpart = 0.0f;
  for (int rr = 0; rr < 8; rr++){
    int row = g*8 + rr;
    const float* xr = x + (size_t)row*512 + l*8;
    float4 xa = *(const float4*)xr;
    float4 xb = *(const float4*)(xr + 4);
    float xe[8] = {xa.x, xa.y, xa.z, xa.w, xb.x, xb.y, xb.z, xb.w};
    float acc[8];
    float sq = 0.0f;
    #pragma unroll
    for (int k = 0; k < 8; k++){
      float a = 0.0f;
      #pragma unroll
      for (int e = 0; e < 8; e++) a += xe[e]*u[k][e];
      acc[k] = a;
    }
    #pragma unroll
    for (int e = 0; e < 8; e++) sq += xe[e]*xe[e];
    // --- reduce-scatter acc[0..7] across 64 lanes (10 DS ops) ---
    if (l & 1){
      float t;
      t=acc[0];acc[0]=acc[4];acc[4]=t;
      t=acc[1];acc[1]=acc[5];acc[5]=t;
      t=acc[2];acc[2]=acc[6];acc[6]=t;
      t=acc[3];acc[3]=acc[7];acc[7]=t;
    }
    acc[0] += __shfl_xor(acc[4], 1, 64);
    acc[1] += __shfl_xor(acc[5], 1, 64);
    acc[2] += __shfl_xor(acc[6], 1, 64);
    acc[3] += __shfl_xor(acc[7], 1, 64);
    if (l & 2){
      float t;
      t=acc[0];acc[0]=acc[2];acc[2]=t;
      t=acc[1];acc[1]=acc[3];acc[3]=t;
    }
    acc[0] += __shfl_xor(acc[2], 2, 64);
    acc[1] += __shfl_xor(acc[3], 2, 64);
    if (l & 4){
      float t=acc[0];acc[0]=acc[1];acc[1]=t;
    }
    acc[0] += __shfl_xor(acc[1], 4, 64);
    acc[0] += __shfl_xor(acc[0], 8, 64);
    acc[0] += __shfl_xor(acc[0], 16, 64);
    acc[0] += __shfl_xor(acc[0], 32, 64);
    // --- full butterfly for sq (6 DS ops) ---
    sq = wred64(sq);
    float vm = vmask[row];
    if (l < 8){
      int b = row >> 14, t = (row >> 7) & 127, n = row & 127;
      int bn = b*128 + n;
      g_ws[OFF_V + bn*1024 + kk*128 + t] = acc[0]*vm;
    }
    if (l == 0) denpart += sqrtf(sq);
  }
  if (l == 0) denw[wv] = denpart;
  __syncthreads();
  if (tid == 0) g_ws[OFF_DENP + blockIdx.x] = denw[0]+denw[1]+denw[2]+denw[3];
}

// ---------------- K3: sort + isotonic soft-sort + quantiles + legendre coeffs -------
__global__ __launch_bounds__(256) void k3_sortfeat(){
  int tid = threadIdx.x;
  int l = tid & 63, wv = tid >> 6;
  int rho = blockIdx.x*4 + wv;         // 0..2047 = bn*8 + k
  __shared__ float orig[4][128], srt[4][128], Bl[384];
  __shared__ float pS[4][128];
  __shared__ int   pC[4][128];
  for (int i = tid; i < 384; i += 256) Bl[i] = g_ws[OFF_LB + i];
  const float* vr = g_ws + OFF_V + rho*128;
  orig[wv][2*l]   = vr[2*l];
  orig[wv][2*l+1] = vr[2*l+1];
  srt[wv][2*l] = 0.0f; srt[wv][2*l+1] = 0.0f;
  __syncthreads();
  float c0, c1, c2;
  {
    float a = orig[wv][2*l], b = orig[wv][2*l+1];
    c0 = a*Bl[2*l]       + b*Bl[2*l+1];
    c1 = a*Bl[128+2*l]   + b*Bl[128+2*l+1];
    c2 = a*Bl[256+2*l]   + b*Bl[256+2*l+1];
  }
  c0 = wred64(c0); c1 = wred64(c1); c2 = wred64(c2);
  // rank sort (stable ascending)
  float e0 = orig[wv][2*l], e1 = orig[wv][2*l+1];
  int r0 = 0, r1 = 0;
  #pragma unroll 4
  for (int j = 0; j < 128; j++){
    float vj = orig[wv][j];
    r0 += (vj < e0) || (vj == e0 && j < 2*l);
    r1 += (vj < e1) || (vj == e1 && j < 2*l+1);
  }
  srt[wv][r0] = e0;
  srt[wv][r1] = e1;
  __syncthreads();
  const float rinv = 22.627416997969522f;  // 1/reg, reg = 0.5*128^-0.5
  bool v0 = (srt[wv][2*l+1] - srt[wv][2*l] > rinv);
  bool v1 = (2*l + 2 < 128) ? (srt[wv][2*l+2] - srt[wv][2*l+1] > rinv) : false;
  if (__any(v0 || v1)){
    if (l == 0){
      int top = -1;
      for (int i = 0; i < 128; i++){
        float y = (float)(128 - i)*rinv + srt[wv][i];
        top++; pS[wv][top] = y; pC[wv][top] = 1;
        while (top > 0 &&
               pS[wv][top]*(float)pC[wv][top-1] > pS[wv][top-1]*(float)pC[wv][top]){
          pS[wv][top-1] += pS[wv][top];
          pC[wv][top-1] += pC[wv][top];
          top--;
        }
      }
      int i = 0;
      for (int blk = 0; blk <= top; blk++){
        float m = pS[wv][blk]/(float)pC[wv][blk];
        for (int c = 0; c < pC[wv][blk]; c++){
          srt[wv][i] = m - (float)(128 - i)*rinv;
          i++;
        }
      }
    }
  }
  if (l == 0){
    int bn = rho >> 3, k = rho & 7;
    float* fb = g_ws + OFF_FEATS + bn*48 + k*6;
    float w0 = 0.1f*127.0f - 12.0f;
    float w1 = 0.5f*127.0f - 63.0f;
    float w2 = 0.9f*127.0f - 114.0f;
    fb[0] = (1.0f - w0)*srt[wv][12]  + w0*srt[wv][13];
    fb[1] = (1.0f - w1)*srt[wv][63]  + w1*srt[wv][64];
    fb[2] = (1.0f - w2)*srt[wv][114] + w2*srt[wv][115];
    fb[3] = c0; fb[4] = c1; fb[5] = c2;
  }
}

// ---------------- K4a: head partials. Block = (bn-pair, f-slice of 6) ---------------
__global__ __launch_bounds__(512) void k4a_head(const float* __restrict__ W1,
                                                const float* __restrict__ b1,
                                                const float* __restrict__ W2){
  int blk = blockIdx.x;                 // 0..1023
  int s   = blk & 7;                    // f-slice: f in [s*6, s*6+6)
  int bnp = blk >> 3;                   // 0..127
  int bn0 = bnp*2, bn1 = bn0 + 1;
  int tid = threadIdx.x;                // = d
  int l = tid & 63, wv = tid >> 6;      // 8 waves
  __shared__ float hl0[96], hl1[96];
  __shared__ float sq[8][12];
  if (tid < 192){
    int which = tid >= 96;
    int i = which ? tid - 96 : tid;     // f_local*16 + w
    int f = s*6 + (i >> 4);
    int k = f*16 + (i & 15);
    int bn = which ? bn1 : bn0;
    float a = g_ws[OFF_FEATS + bn*48 + f]*W1[k] + b1[k];
    float g = 0.5f*a*(1.0f + erff(a*0.70710678118654752f));  // exact GELU
    if (which) hl1[i] = g; else hl0[i] = g;
  }
  __syncthreads();
  int d = tid;
  float b2 = g_ws[OFF_B2 + d];
  float y0 = 0.0f, y1 = 0.0f;
  const float* w2base = W2 + (size_t)(s*96)*512 + d;
  #pragma unroll
  for (int fl_ = 0; fl_ < 6; fl_++){
    float p0 = 0.0f, p1 = 0.0f;
    #pragma unroll
    for (int w = 0; w < 16; w++){
      float w2 = w2base[(size_t)(fl_*16 + w)*512];
      p0 += hl0[fl_*16 + w]*w2;
      p1 += hl1[fl_*16 + w]*w2;
    }
    y0 += p0; y1 += p1;
    float e0 = wred64(p0*p0*b2);
    float e1 = wred64(p1*p1*b2);
    if (l == 0){ sq[wv][fl_*2] = e0; sq[wv][fl_*2 + 1] = e1; }
  }
  g_ws[OFF_YP + (size_t)(bn0*8 + s)*512 + d] = y0;
  g_ws[OFF_YP + (size_t)(bn1*8 + s)*512 + d] = y1;
  __syncthreads();
  if (tid < 12){
    float t = 0.0f;
    #pragma unroll
    for (int w = 0; w < 8; w++) t += sq[w][tid];
    int fl_ = tid >> 1, which = tid & 1;
    int bn = which ? bn1 : bn0;
    g_ws[OFF_SQP + bn*48 + s*6 + fl_] = t;
  }
}

// ---------------- K4b: y = sum of slice partials; num per bn ------------------------
__global__ __launch_bounds__(512) void k4b_red(){
  int bn = blockIdx.x;
  int tid = threadIdx.x;
  int l = tid & 63, wv = tid >> 6;
  __shared__ float nw[8];
  float y = 0.0f;
  #pragma unroll
  for (int s = 0; s < 8; s++) y += g_ws[OFF_YP + (size_t)(bn*8 + s)*512 + tid];
  g_ws[OFF_Y + bn*512 + tid] = y;
  float be = g_ws[OFF_BEFF + tid];
  float by = be*y;
  float ns = wred64(by*by);
  if (l == 0) nw[wv] = ns;
  __syncthreads();
  if (tid == 0){
    float s = nw[0]+nw[1]+nw[2]+nw[3]+nw[4]+nw[5]+nw[6]+nw[7];
    g_ws[OFF_NUMP + bn] = sqrtf(s);
  }
}

// ---------------- K7: h epilogue; block 16384 additionally finalizes r/r_feat -------
__global__ __launch_bounds__(256) void k7_out(const float* __restrict__ x,
                                              const float* __restrict__ vmask,
                                              float* __restrict__ outt){
  if (blockIdx.x == 16384){
    // ---- former k6: finalize r and r_feat ----
    __shared__ float red[256];
    __shared__ float en[96];
    __shared__ float scal[2];
    int tid = threadIdx.x;
    float dp = 0.0f;
    for (int i = tid; i < 1024; i += 256) dp += g_ws[OFF_DENP + i];
    red[tid] = dp; __syncthreads();
    for (int s = 128; s > 0; s >>= 1){
      if (tid < s) red[tid] += red[tid + s];
      __syncthreads();
    }
    if (tid == 0) scal[0] = fmaxf(red[0]/32768.0f, 1e-9f);
    __syncthreads();
    red[tid] = g_ws[OFF_NUMP + tid];
    __syncthreads();
    for (int s = 128; s > 0; s >>= 1){
      if (tid < s) red[tid] += red[tid + s];
      __syncthreads();
    }
    if (tid == 0) scal[1] = red[0]/256.0f;
    __syncthreads();
    float den = scal[0];
    if (tid < 96){
      int b = tid/48, f = tid%48;
      float s = 0.0f;
      for (int j = 0; j < 128; j++) s += g_ws[OFF_SQP + (b*128 + j)*48 + f];
      en[tid] = sqrtf(128.0f*s);
    }
    __syncthreads();
    if (tid == 0) outt[16777216] = scal[1]/den;
    if (tid < 48) outt[16777217 + tid] = 0.5f*(en[tid] + en[48 + tid])/den;
    return;
  }
  int q = blockIdx.x*256 + threadIdx.x;  // quad id < 4194304
  size_t fl = (size_t)q*4;
  int d = (int)(fl & 511);
  int row = (int)(fl >> 9);
  int b = row >> 14, n = row & 127;
  int bn = b*128 + n;
  float vm = vmask[row];
  float4 xv = *(const float4*)(x + fl);
  float4 yv = *(const float4*)(g_ws + OFF_Y + bn*512 + d);
  float4 bv = *(const float4*)(g_ws + OFF_BEFF + d);
  float4 o;
  o.x = xv.x + vm*bv.x*yv.x;
  o.y = xv.y + vm*bv.y*yv.y;
  o.z = xv.z + vm*bv.z*yv.z;
  o.w = xv.w + vm*bv.w*yv.w;
  *(float4*)(outt + fl) = o;
}

extern "C" void kernel_launch(void* const* d_in, const int* in_sizes, int n_in,
                              void* d_out, int out_size, void* d_ws, size_t ws_size,
                              hipStream_t stream){
  (void)out_size; (void)d_ws; (void)ws_size;
  const float *x=nullptr,*vm=nullptr,*Wp=nullptr,*W1=nullptr,*b1=nullptr,*W2=nullptr,*beta=nullptr;
  for (int i = 0; i < n_in; i++){
    int s = in_sizes[i];
    const float* p = (const float*)d_in[i];
    if      (s == 16777216) x = p;
    else if (s == 32768)    vm = p;
    else if (s == 4096)     Wp = p;
    else if (s == 393216)   W2 = p;
    else if (s == 512)      beta = p;
    else if (s == 768)      { if (!W1) W1 = p; else b1 = p; }
  }
  float* out = (float*)d_out;

  k1_prep<<<1, 256, 0, stream>>>(Wp, beta);
  k2_proj<<<1024, 256, 0, stream>>>(x, vm);
  k3_sortfeat<<<512, 256, 0, stream>>>();
  k4a_head<<<1024, 512, 0, stream>>>(W1, b1, W2);
  k4b_red<<<256, 512, 0, stream>>>();
  k7_out<<<16385, 256, 0, stream>>>(x, vm, out);
}